// Round 4
// baseline (832.334 us; speedup 1.0000x reference)
//
#include <hip/hip_runtime.h>

typedef unsigned short u16;
typedef unsigned int   u32;
typedef __bf16 bf16x8 __attribute__((ext_vector_type(8)));
typedef float  f32x4  __attribute__((ext_vector_type(4)));
typedef u16    u16x8  __attribute__((ext_vector_type(8)));

#define S_   2048
#define D_   1024
#define H_   16
#define M_   4096

// log2-domain softmax: p = exp2(s*SCALE2 + mask*MASKC - SHIFT2)
// fixed shift 8 replaces the row max (softmax shift-invariant; |s*0.125|<~12)
#define SCALE2 0.18033688011112042f
#define MASKC  (-1.4426950408889634e9f)
#define SHIFT2 11.541560327111707f

__device__ __forceinline__ u16 f2b(float f){
  union { float f; u32 i; } x; x.f = f;
  u32 u = x.i;
  u32 r = (u + 0x7fffu + ((u >> 16) & 1u)) >> 16;
  return (u16)r;
}
__device__ __forceinline__ void async16(u16* lds, const u16* g){
  __builtin_amdgcn_global_load_lds((const __attribute__((address_space(1))) void*)g,
                                   (__attribute__((address_space(3))) void*)lds, 16, 0, 0);
}
__device__ __forceinline__ f32x4 mma16(bf16x8 a, bf16x8 b, f32x4 c){
  return __builtin_amdgcn_mfma_f32_16x16x32_bf16(a, b, c, 0, 0, 0);
}
__device__ __forceinline__ bf16x8 ld_frag_u16(const u16* p){
  u16x8 v = *(const u16x8*)p;
  return __builtin_bit_cast(bf16x8, v);
}

// ---------------------------------------------------------------------------
// prep: fused  (a) q/k/v fp32->bf16 cvt   [blocks 0..6143]
//              (b) weight transpose+cvt   [blocks 6144..7167]
// ---------------------------------------------------------------------------
__global__ __launch_bounds__(256) void prep(
    const float* __restrict__ q, const float* __restrict__ k, const float* __restrict__ v,
    u16* __restrict__ qb, u16* __restrict__ kb, u16* __restrict__ vb,
    const float* __restrict__ w0, const float* __restrict__ w1,
    const float* __restrict__ w2, const float* __restrict__ w3,
    u16* __restrict__ t0, u16* __restrict__ t1,
    u16* __restrict__ t2, u16* __restrict__ t3)
{
  const int bid = blockIdx.x;
  if (bid < 6144){
    const int which = bid >> 11;
    const int bx = bid & 2047;
    const float* x = (which == 0) ? q : (which == 1) ? k : v;
    u16* y = (which == 0) ? qb : (which == 1) ? kb : vb;
    size_t i = (size_t)bx * 256 + threadIdx.x;
    const f32x4* p = (const f32x4*)(x + i * 8);
    f32x4 a = p[0], b = p[1];
    u16x8 o;
    o[0] = f2b(a[0]); o[1] = f2b(a[1]); o[2] = f2b(a[2]); o[3] = f2b(a[3]);
    o[4] = f2b(b[0]); o[5] = f2b(b[1]); o[6] = f2b(b[2]); o[7] = f2b(b[3]);
    *(u16x8*)(y + i * 8) = o;
  } else {
    const int b = bid - 6144;
    const int z = b >> 8, rem = b & 255, by = rem >> 4, bx = rem & 15;
    const float* W; u16* T;
    switch (z){
      case 0: W = w0; T = t0; break;
      case 1: W = w1; T = t1; break;
      case 2: W = w2; T = t2; break;
      default: W = w3; T = t3; break;
    }
    __shared__ u16 tile[64][65];
    const int t = threadIdx.x;
    const int r0 = by * 64, c0 = bx * 64;
    const int row = t >> 2, cg = t & 3;
    const float* src = W + (size_t)(r0 + row) * D_ + c0 + cg * 16;
    f32x4 a0 = *(const f32x4*)(src + 0);
    f32x4 a1 = *(const f32x4*)(src + 4);
    f32x4 a2 = *(const f32x4*)(src + 8);
    f32x4 a3 = *(const f32x4*)(src + 12);
    #pragma unroll
    for (int e = 0; e < 4; ++e){
      tile[row][cg*16 +      e] = f2b(a0[e]);
      tile[row][cg*16 +  4 + e] = f2b(a1[e]);
      tile[row][cg*16 +  8 + e] = f2b(a2[e]);
      tile[row][cg*16 + 12 + e] = f2b(a3[e]);
    }
    __syncthreads();
    u16* dst = T + (size_t)(c0 + row) * D_ + r0 + cg * 16;
    u16x8 oa, ob;
    #pragma unroll
    for (int e = 0; e < 8; ++e){ oa[e] = tile[cg*16 + e][row]; ob[e] = tile[cg*16 + 8 + e][row]; }
    *(u16x8*)dst = oa;
    *(u16x8*)(dst + 8) = ob;
  }
}

// ---------------------------------------------------------------------------
// gemm_qkv: fused Q/K/V projections, double-buffered LDS prefetch (64 KB).
// Epilogue round-trips the 128x128 C tile through LDS for 16B-coalesced
// stores; z==2 writes the tile TRANSPOSED, producing Vt [bh,64,S] directly.
// ---------------------------------------------------------------------------
__global__ __launch_bounds__(256) void gemm_qkv(
    const u16* __restrict__ qb, const u16* __restrict__ kb, const u16* __restrict__ vb,
    const u16* __restrict__ wqT, const u16* __restrict__ wkT, const u16* __restrict__ wvT,
    const float* __restrict__ bq, const float* __restrict__ bk, const float* __restrict__ bv,
    u16* __restrict__ Qh, u16* __restrict__ Kh, u16* __restrict__ Vt)
{
  // layout: As[2] at 0,8192 ; Bs[2] at 16384,24576 (u16 units). 64 KB total.
  // Epilogue reuses [0 .. 16895] as the 128x132 C tile.
  __shared__ __attribute__((aligned(16))) u16 smem[32768];
  const u16 *A, *Bt; const float* bias; u16* Cb;
  switch (blockIdx.z){
    case 0: A = qb; Bt = wqT; bias = bq; Cb = Qh; break;
    case 1: A = kb; Bt = wkT; bias = bk; Cb = Kh; break;
    default: A = vb; Bt = wvT; bias = bv; Cb = Vt; break;
  }
  const bool vtr = (blockIdx.z == 2);
  const int tid = threadIdx.x;
  const int wave = tid >> 6, lane = tid & 63, ln = lane & 15, quad = lane >> 4;
  const int wm = wave >> 1, wn = wave & 1;
  const int m0 = blockIdx.x * 128, n0 = blockIdx.y * 128;

  f32x4 acc[4][4];
  #pragma unroll
  for (int i = 0; i < 4; ++i)
    #pragma unroll
    for (int j = 0; j < 4; ++j) acc[i][j] = (f32x4){0.f, 0.f, 0.f, 0.f};

  // preload tile kt=0 into buffer 0
  #pragma unroll
  for (int it = 0; it < 4; ++it){
    int i = it * 256 + tid;
    int r = i >> 3, c = i & 7, cs = c ^ (r & 7);
    async16(&smem[i * 8],         &A [(size_t)(m0 + r) * D_ + cs * 8]);
    async16(&smem[16384 + i * 8], &Bt[(size_t)(n0 + r) * D_ + cs * 8]);
  }
  __syncthreads();

  int cur = 0;
  for (int kt = 0; kt < D_; kt += 64){
    if (kt + 64 < D_){
      u16* An = &smem[(cur ^ 1) * 8192];
      u16* Bn = &smem[16384 + (cur ^ 1) * 8192];
      #pragma unroll
      for (int it = 0; it < 4; ++it){
        int i = it * 256 + tid;
        int r = i >> 3, c = i & 7, cs = c ^ (r & 7);
        async16(&An[i * 8], &A [(size_t)(m0 + r) * D_ + kt + 64 + cs * 8]);
        async16(&Bn[i * 8], &Bt[(size_t)(n0 + r) * D_ + kt + 64 + cs * 8]);
      }
    }
    const u16* Ac = &smem[cur * 8192];
    const u16* Bc = &smem[16384 + cur * 8192];
    #pragma unroll
    for (int kk = 0; kk < 2; ++kk){
      bf16x8 af[4], bfr[4];
      #pragma unroll
      for (int i4 = 0; i4 < 4; ++i4){
        int row = wm * 64 + i4 * 16 + ln;
        af[i4] = ld_frag_u16(&Ac[row * 64 + ((kk * 4 + quad) ^ (row & 7)) * 8]);
      }
      #pragma unroll
      for (int j4 = 0; j4 < 4; ++j4){
        int row = wn * 64 + j4 * 16 + ln;
        bfr[j4] = ld_frag_u16(&Bc[row * 64 + ((kk * 4 + quad) ^ (row & 7)) * 8]);
      }
      #pragma unroll
      for (int i4 = 0; i4 < 4; ++i4)
        #pragma unroll
        for (int j4 = 0; j4 < 4; ++j4)
          acc[i4][j4] = mma16(af[i4], bfr[j4], acc[i4][j4]);
    }
    __syncthreads();
    cur ^= 1;
  }

  // ---- epilogue: bias add -> bf16 -> LDS tile -> coalesced 16B stores ----
  #pragma unroll
  for (int j4 = 0; j4 < 4; ++j4){
    int nl = wn * 64 + j4 * 16 + ln;
    float biasv = bias[n0 + nl];
    #pragma unroll
    for (int i4 = 0; i4 < 4; ++i4){
      #pragma unroll
      for (int rg = 0; rg < 4; ++rg){
        int ml = wm * 64 + i4 * 16 + quad * 4 + rg;
        u16 hv = f2b(acc[i4][j4][rg] + biasv);
        smem[vtr ? (nl * 132 + ml) : (ml * 132 + nl)] = hv;
      }
    }
  }
  __syncthreads();
  const int bb = m0 >> 11, sbase = m0 & 2047;
  #pragma unroll
  for (int c = 0; c < 8; ++c){
    int task = c * 256 + tid;         // 0..2047: 128 rows x 16 chunks of 8 u16
    int rr = task >> 4, ch = task & 15;
    u16x8 val = *(const u16x8*)&smem[rr * 132 + ch * 8];
    if (vtr){
      int hh = (n0 + rr) >> 6, dc = (n0 + rr) & 63;
      *(u16x8*)&Cb[((size_t)(bb * H_ + hh) * 64 + dc) * S_ + sbase + ch * 8] = val;
    } else {
      int s = sbase + rr;
      int nn = n0 + ch * 8, hh = nn >> 6, dc = nn & 63;
      *(u16x8*)&Cb[((size_t)(bb * H_ + hh) * S_ + s) * 64 + dc] = val;
    }
  }
}

// ---------------------------------------------------------------------------
// gemm_o: output projection, fp32 C. Double-buffered LDS prefetch.
// ---------------------------------------------------------------------------
__global__ __launch_bounds__(256) void gemm_o(
    const u16* __restrict__ A, const u16* __restrict__ Bt,
    const float* __restrict__ bias, float* __restrict__ Cf)
{
  __shared__ __attribute__((aligned(16))) u16 As[2][128 * 64];
  __shared__ __attribute__((aligned(16))) u16 Bs[2][128 * 64];
  const int tid = threadIdx.x;
  const int wave = tid >> 6, lane = tid & 63, ln = lane & 15, quad = lane >> 4;
  const int wm = wave >> 1, wn = wave & 1;
  const int m0 = blockIdx.x * 128, n0 = blockIdx.y * 128;

  f32x4 acc[4][4];
  #pragma unroll
  for (int i = 0; i < 4; ++i)
    #pragma unroll
    for (int j = 0; j < 4; ++j) acc[i][j] = (f32x4){0.f, 0.f, 0.f, 0.f};

  #pragma unroll
  for (int it = 0; it < 4; ++it){
    int i = it * 256 + tid;
    int r = i >> 3, c = i & 7, cs = c ^ (r & 7);
    async16(&As[0][i * 8], &A [(size_t)(m0 + r) * D_ + cs * 8]);
    async16(&Bs[0][i * 8], &Bt[(size_t)(n0 + r) * D_ + cs * 8]);
  }
  __syncthreads();

  int cur = 0;
  for (int kt = 0; kt < D_; kt += 64){
    if (kt + 64 < D_){
      int nb = cur ^ 1;
      #pragma unroll
      for (int it = 0; it < 4; ++it){
        int i = it * 256 + tid;
        int r = i >> 3, c = i & 7, cs = c ^ (r & 7);
        async16(&As[nb][i * 8], &A [(size_t)(m0 + r) * D_ + kt + 64 + cs * 8]);
        async16(&Bs[nb][i * 8], &Bt[(size_t)(n0 + r) * D_ + kt + 64 + cs * 8]);
      }
    }
    #pragma unroll
    for (int kk = 0; kk < 2; ++kk){
      bf16x8 af[4], bfr[4];
      #pragma unroll
      for (int i4 = 0; i4 < 4; ++i4){
        int row = wm * 64 + i4 * 16 + ln;
        af[i4] = ld_frag_u16(&As[cur][row * 64 + ((kk * 4 + quad) ^ (row & 7)) * 8]);
      }
      #pragma unroll
      for (int j4 = 0; j4 < 4; ++j4){
        int row = wn * 64 + j4 * 16 + ln;
        bfr[j4] = ld_frag_u16(&Bs[cur][row * 64 + ((kk * 4 + quad) ^ (row & 7)) * 8]);
      }
      #pragma unroll
      for (int i4 = 0; i4 < 4; ++i4)
        #pragma unroll
        for (int j4 = 0; j4 < 4; ++j4)
          acc[i4][j4] = mma16(af[i4], bfr[j4], acc[i4][j4]);
    }
    __syncthreads();
    cur ^= 1;
  }

  #pragma unroll
  for (int j4 = 0; j4 < 4; ++j4){
    int nidx = n0 + wn * 64 + j4 * 16 + ln;
    float biasv = bias[nidx];
    #pragma unroll
    for (int i4 = 0; i4 < 4; ++i4){
      #pragma unroll
      for (int rg = 0; rg < 4; ++rg){
        int r = m0 + wm * 64 + i4 * 16 + quad * 4 + rg;
        Cf[(size_t)r * D_ + nidx] = acc[i4][j4][rg] + biasv;
      }
    }
  }
}

// ---------------------------------------------------------------------------
// Pass 1: softmax denominator, fixed shift. QBLK=128, double-buffered K
// staging, XCD-pinned bh. Grid: 512 blocks flattened.
// ---------------------------------------------------------------------------
__global__ __launch_bounds__(256) void attn_stats(
    const u16* __restrict__ Qh, const u16* __restrict__ Kh,
    const float* __restrict__ maskp, float* __restrict__ lrow)
{
  __shared__ __attribute__((aligned(16))) u16 Qs[128 * 64];
  __shared__ __attribute__((aligned(16))) u16 Ks[2][64 * 64];
  const int tid = threadIdx.x;
  const int wave = tid >> 6, lane = tid & 63, ln = lane & 15, quad = lane >> 4;
  const int orig = blockIdx.x;          // 512
  const int xcd = orig & 7, slot = orig >> 3;
  const int bh = xcd * 4 + (slot >> 4); // 4 bh per XCD
  const int q0 = (slot & 15) * 128;
  const int bsel = bh >> 4;

  #pragma unroll
  for (int it = 0; it < 4; ++it){
    int i = it * 256 + tid;
    int r = i >> 3, c = i & 7, cs = c ^ (r & 7);
    async16(&Qs[i * 8], &Qh[((size_t)bh * S_ + q0 + r) * 64 + cs * 8]);
  }
  #pragma unroll
  for (int it = 0; it < 2; ++it){
    int i = it * 256 + tid;
    int r = i >> 3, c = i & 7, cs = c ^ (r & 7);
    async16(&Ks[0][i * 8], &Kh[((size_t)bh * S_ + r) * 64 + cs * 8]);
  }
  __syncthreads();
  bf16x8 aq[2][2];
  #pragma unroll
  for (int f = 0; f < 2; ++f){
    int row = wave * 32 + f * 16 + ln;
    aq[f][0] = ld_frag_u16(&Qs[row * 64 + ((0 + quad) ^ (row & 7)) * 8]);
    aq[f][1] = ld_frag_u16(&Qs[row * 64 + ((4 + quad) ^ (row & 7)) * 8]);
  }

  float lsum[2][4] = {{0.f,0.f,0.f,0.f},{0.f,0.f,0.f,0.f}};
  int cur = 0;
  for (int n0 = 0; n0 < S_; n0 += 64){
    if (n0 + 64 < S_){
      int nb = cur ^ 1;
      #pragma unroll
      for (int it = 0; it < 2; ++it){
        int i = it * 256 + tid;
        int r = i >> 3, c = i & 7, cs = c ^ (r & 7);
        async16(&Ks[nb][i * 8], &Kh[((size_t)bh * S_ + n0 + 64 + r) * 64 + cs * 8]);
      }
    }
    float mv[4];
    #pragma unroll
    for (int j = 0; j < 4; ++j)
      mv[j] = maskp[bsel * S_ + n0 + j * 16 + ln] * MASKC - SHIFT2;
    #pragma unroll
    for (int j = 0; j < 4; ++j){
      int row = j * 16 + ln;
      bf16x8 b0 = ld_frag_u16(&Ks[cur][row * 64 + ((0 + quad) ^ (row & 7)) * 8]);
      bf16x8 b1 = ld_frag_u16(&Ks[cur][row * 64 + ((4 + quad) ^ (row & 7)) * 8]);
      #pragma unroll
      for (int f = 0; f < 2; ++f){
        f32x4 a = {0.f, 0.f, 0.f, 0.f};
        a = mma16(aq[f][0], b0, a);
        a = mma16(aq[f][1], b1, a);
        #pragma unroll
        for (int rg = 0; rg < 4; ++rg)
          lsum[f][rg] += exp2f(a[rg] * SCALE2 + mv[j]);
      }
    }
    __syncthreads();
    cur ^= 1;
  }
  #pragma unroll
  for (int f = 0; f < 2; ++f)
    #pragma unroll
    for (int rg = 0; rg < 4; ++rg){
      float s = lsum[f][rg];
      s += __shfl_xor(s, 1);
      s += __shfl_xor(s, 2);
      s += __shfl_xor(s, 4);
      s += __shfl_xor(s, 8);
      if (ln == 0)
        lrow[bh * S_ + q0 + wave * 32 + f * 16 + quad * 4 + rg] = s;
    }
}

// ---------------------------------------------------------------------------
// Pass 2: QBLK=128, K/V double-buffered in LDS, per-wave Ps round-trip.
// Barrier is counted: s_waitcnt vmcnt(24) completes the (oldest) stage loads
// while leaving ~24 attn stores in flight across the barrier — removes the
// per-tile store drain that __syncthreads (vmcnt(0)) would impose.
// attn stores are nontemporal so the 512 MB stream doesn't evict K/V from L2.
// ---------------------------------------------------------------------------
__global__ __launch_bounds__(256) void attn_pv(
    const u16* __restrict__ Qh, const u16* __restrict__ Kh, const u16* __restrict__ Vt,
    const float* __restrict__ maskp, const float* __restrict__ lrow,
    float* __restrict__ attn, u16* __restrict__ OH)
{
  __shared__ __attribute__((aligned(16))) u16 Ks[2][64 * 64];
  __shared__ __attribute__((aligned(16))) u16 Vs[2][64 * 64];
  __shared__ __attribute__((aligned(16))) u16 Ps[4][32 * 72];
  const int tid = threadIdx.x;
  const int wave = tid >> 6, lane = tid & 63, ln = lane & 15, quad = lane >> 4;
  const int orig = blockIdx.x;          // 512
  const int xcd = orig & 7, slot = orig >> 3;
  const int bh = xcd * 4 + (slot >> 4);
  const int q0 = (slot & 15) * 128;
  const int bsel = bh >> 4;

  bf16x8 aq[2][2];
  #pragma unroll
  for (int f = 0; f < 2; ++f){
    const u16* qp = &Qh[((size_t)bh * S_ + q0 + wave * 32 + f * 16 + ln) * 64 + quad * 8];
    aq[f][0] = ld_frag_u16(qp);
    aq[f][1] = ld_frag_u16(qp + 32);
  }
  float il[2][4];
  #pragma unroll
  for (int f = 0; f < 2; ++f)
    #pragma unroll
    for (int rg = 0; rg < 4; ++rg){
      int row = q0 + wave * 32 + f * 16 + quad * 4 + rg;
      il[f][rg] = 1.0f / lrow[bh * S_ + row];
    }
  f32x4 oacc[2][4];
  #pragma unroll
  for (int f = 0; f < 2; ++f)
    #pragma unroll
    for (int jd = 0; jd < 4; ++jd) oacc[f][jd] = (f32x4){0.f, 0.f, 0.f, 0.f};

  #pragma unroll
  for (int it = 0; it < 2; ++it){
    int i = it * 256 + tid;
    int r = i >> 3, c = i & 7, cs = c ^ (r & 7);
    async16(&Ks[0][i * 8], &Kh[((size_t)bh * S_ + r) * 64 + cs * 8]);
    async16(&Vs[0][i * 8], &Vt[((size_t)bh * 64 + r) * S_ + cs * 8]);
  }
  __syncthreads();

  int cur = 0;
  for (int n0 = 0; n0 < S_; n0 += 64){
    if (n0 + 64 < S_){
      int nb = cur ^ 1;
      #pragma unroll
      for (int it = 0; it < 2; ++it){
        int i = it * 256 + tid;
        int r = i >> 3, c = i & 7, cs = c ^ (r & 7);
        async16(&Ks[nb][i * 8], &Kh[((size_t)bh * S_ + n0 + 64 + r) * 64 + cs * 8]);
        async16(&Vs[nb][i * 8], &Vt[((size_t)bh * 64 + r) * S_ + n0 + 64 + cs * 8]);
      }
    }
    float mv[4];
    #pragma unroll
    for (int j = 0; j < 4; ++j)
      mv[j] = maskp[bsel * S_ + n0 + j * 16 + ln] * MASKC - SHIFT2;
    #pragma unroll
    for (int j = 0; j < 4; ++j){
      int row = j * 16 + ln;
      bf16x8 b0 = ld_frag_u16(&Ks[cur][row * 64 + ((0 + quad) ^ (row & 7)) * 8]);
      bf16x8 b1 = ld_frag_u16(&Ks[cur][row * 64 + ((4 + quad) ^ (row & 7)) * 8]);
      #pragma unroll
      for (int f = 0; f < 2; ++f){
        f32x4 a = {0.f, 0.f, 0.f, 0.f};
        a = mma16(aq[f][0], b0, a);
        a = mma16(aq[f][1], b1, a);
        #pragma unroll
        for (int rg = 0; rg < 4; ++rg){
          float p = exp2f(a[rg] * SCALE2 + mv[j]) * il[f][rg];
          __builtin_nontemporal_store(
              p, &attn[((size_t)bh * S_ + q0 + wave * 32 + f * 16 + quad * 4 + rg) * S_ + n0 + j * 16 + ln]);
          Ps[wave][(f * 16 + quad * 4 + rg) * 72 + j * 16 + ln] = f2b(p);
        }
      }
    }
    // Ps is per-wave: ds_write -> ds_read ordering via lgkmcnt, no barrier.
    #pragma unroll
    for (int f = 0; f < 2; ++f){
      #pragma unroll
      for (int kk = 0; kk < 2; ++kk){
        bf16x8 pa = ld_frag_u16(&Ps[wave][(f * 16 + ln) * 72 + kk * 32 + quad * 8]);
        #pragma unroll
        for (int jd = 0; jd < 4; ++jd){
          int row = jd * 16 + ln;
          bf16x8 vb = ld_frag_u16(&Vs[cur][row * 64 + ((kk * 4 + quad) ^ (row & 7)) * 8]);
          oacc[f][jd] = mma16(pa, vb, oacc[f][jd]);
        }
      }
    }
    if (n0 + 64 < S_){
      // counted barrier: complete the 4 (oldest) stage loads; leave stores in flight
      asm volatile("s_waitcnt vmcnt(24) lgkmcnt(0)" ::: "memory");
      __builtin_amdgcn_s_barrier();
      __builtin_amdgcn_sched_barrier(0);
    }
    cur ^= 1;
  }
  const int b = bh >> 4, h = bh & 15;
  #pragma unroll
  for (int f = 0; f < 2; ++f)
    #pragma unroll
    for (int jd = 0; jd < 4; ++jd)
      #pragma unroll
      for (int rg = 0; rg < 4; ++rg){
        int row = q0 + wave * 32 + f * 16 + quad * 4 + rg;
        OH[((size_t)b * S_ + row) * D_ + h * 64 + jd * 16 + ln] = f2b(oacc[f][jd][rg]);
      }
}

// ---------------------------------------------------------------------------
extern "C" void kernel_launch(void* const* d_in, const int* in_sizes, int n_in,
                              void* d_out, int out_size, void* d_ws, size_t ws_size,
                              hipStream_t stream)
{
  const float* q    = (const float*)d_in[0];
  const float* k    = (const float*)d_in[1];
  const float* v    = (const float*)d_in[2];
  const float* mask = (const float*)d_in[3];
  const float* wq   = (const float*)d_in[4];
  const float* bq   = (const float*)d_in[5];
  const float* wk   = (const float*)d_in[6];
  const float* bk   = (const float*)d_in[7];
  const float* wv   = (const float*)d_in[8];
  const float* bv   = (const float*)d_in[9];
  const float* wo   = (const float*)d_in[10];
  const float* bo   = (const float*)d_in[11];

  char* ws = (char*)d_ws;
  u16* wqT = (u16*)(ws + 0ull);
  u16* wkT = (u16*)(ws + 2097152ull);
  u16* wvT = (u16*)(ws + 4194304ull);
  u16* woT = (u16*)(ws + 6291456ull);
  u16* qb  = (u16*)(ws + 8388608ull);
  u16* kb  = (u16*)(ws + 16777216ull);
  u16* vb  = (u16*)(ws + 25165824ull);
  u16* Qh  = (u16*)(ws + 33554432ull);
  u16* Kh  = (u16*)(ws + 41943040ull);
  u16* Vt  = (u16*)(ws + 50331648ull);
  u16* OH  = (u16*)(ws + 58720256ull);
  float* lrow = (float*)(ws + 67108864ull);

  float* out  = (float*)d_out;
  float* attn = out + 4194304ull;  // [B,H,S,S] fp32

  prep<<<dim3(7168), 256, 0, stream>>>(q, k, v, qb, kb, vb,
                                       wq, wk, wv, wo, wqT, wkT, wvT, woT);
  gemm_qkv<<<dim3(32, 8, 3), 256, 0, stream>>>(qb, kb, vb, wqT, wkT, wvT,
                                               bq, bk, bv, Qh, Kh, Vt);
  attn_stats<<<dim3(512), 256, 0, stream>>>(Qh, Kh, mask, lrow);
  attn_pv<<<dim3(512), 256, 0, stream>>>(Qh, Kh, Vt, mask, lrow, attn, OH);
  gemm_o<<<dim3(32, 8), 256, 0, stream>>>(OH, woT, bo, out);
}